// Round 12
// baseline (221.794 us; speedup 1.0000x reference)
//
#include <hip/hip_runtime.h>
#include <hip/hip_bf16.h>

typedef __bf16 bf16_t;
typedef __bf16 bf16x4 __attribute__((ext_vector_type(4)));
typedef __bf16 bf16x8 __attribute__((ext_vector_type(8)));
typedef float floatx4 __attribute__((ext_vector_type(4)));

#define SEQ    8192
#define DM     1024
#define NHEADS 16
#define HDIM   64

// async global->LDS, 16B per lane; LDS dest is wave-uniform base + lane*16
__device__ __forceinline__ void async_ld16(bf16_t* lds, const bf16_t* g) {
  __builtin_amdgcn_global_load_lds(
      (__attribute__((address_space(1))) void*)g,
      (__attribute__((address_space(3))) void*)lds, 16, 0, 0);
}

// one launch converts x (8192 blocks) + 4 weight matrices (1024 blocks each)
__global__ __launch_bounds__(256)
void cvt_all(const float* __restrict__ x,  const float* __restrict__ qw,
             const float* __restrict__ kw, const float* __restrict__ vw,
             const float* __restrict__ ow,
             bf16_t* __restrict__ Xb,  bf16_t* __restrict__ QWb,
             bf16_t* __restrict__ KWb, bf16_t* __restrict__ VWb,
             bf16_t* __restrict__ OWb) {
  const int b = blockIdx.x;
  const float* in; bf16_t* out; int g;
  if (b < 8192) { in = x; out = Xb; g = b; }
  else {
    const int w  = (b - 8192) >> 10;
    const int wb = (b - 8192) & 1023;
    switch (w) {
      case 0:  in = qw; out = QWb; break;
      case 1:  in = kw; out = KWb; break;
      case 2:  in = vw; out = VWb; break;
      default: in = ow; out = OWb; break;
    }
    g = wb;
  }
  const int idx = (g * 256 + threadIdx.x) * 4;
  float4 v = *(const float4*)(in + idx);
  bf16x4 o = { (bf16_t)v.x, (bf16_t)v.y, (bf16_t)v.z, (bf16_t)v.w };
  *(bf16x4*)(out + idx) = o;
}

// BK=64 XOR-8 swizzle: row stride 64 elem (128 B = 8 chunks of 16 B).
// LDS slot c of row r holds global chunk c ^ (r&7). Read: chunk g of row r at
// slot g^(r&7) -> 16 rows of a b128 read cover all 8 bank-groups 2-way (free).
// Staging lane L: row L>>3, slot L&7 -> fetches global chunk (L&7)^((L>>3)&7)
// (permutation within the row's 128 B segment; coalescing + contiguous
// lane*16B LDS dest preserved). Round 7's BK=64 regression was the UNswizzled
// 8-way conflict (1.89e7), not occupancy -- this composes the round-8 fix.

// ---------- QKV projection: 128x128 tile, BK=64 (16 barrier-pairs), swizzled ----------
__global__ __launch_bounds__(256)
void gemm_qkv(const bf16_t* __restrict__ A,
              const bf16_t* __restrict__ Bq, const bf16_t* __restrict__ Bk,
              const bf16_t* __restrict__ Bv,
              bf16_t* __restrict__ Cq, bf16_t* __restrict__ Ck, bf16_t* __restrict__ Cv)
{
  const bf16_t* B = (blockIdx.z == 0) ? Bq : (blockIdx.z == 1) ? Bk : Bv;
  bf16_t*       C = (blockIdx.z == 0) ? Cq : (blockIdx.z == 1) ? Ck : Cv;
  constexpr int Kdim = DM;
  __shared__ __attribute__((aligned(16))) bf16_t sA[128 * 64];   // 16 KB
  __shared__ __attribute__((aligned(16))) bf16_t sB[128 * 64];   // 16 KB

  const int tid  = threadIdx.x;
  const int wave = tid >> 6;
  const int lane = tid & 63;
  const int quad = lane >> 4;
  const int r16  = lane & 15;
  const int wr   = (wave >> 1) * 64;
  const int wc   = (wave & 1) * 64;

  const int gc = (lane & 7) ^ ((lane >> 3) & 7);   // swizzled fetch chunk
  const size_t arow0 = (size_t)blockIdx.x * 128 + wave * 32 + (lane >> 3);
  const size_t brow0 = (size_t)blockIdx.y * 128 + wave * 32 + (lane >> 3);
  const bf16_t* Ag = A + arow0 * Kdim + gc * 8;
  const bf16_t* Bg = B + brow0 * Kdim + gc * 8;
  bf16_t* sAw = sA + wave * 32 * 64;
  bf16_t* sBw = sB + wave * 32 * 64;

  floatx4 acc[4][4];
  #pragma unroll
  for (int i = 0; i < 4; ++i)
    #pragma unroll
    for (int j = 0; j < 4; ++j)
      acc[i][j] = (floatx4)(0.0f);

  for (int ko = 0; ko < Kdim; ko += 64) {
    #pragma unroll
    for (int n = 0; n < 4; ++n) {
      async_ld16(sAw + n * 512, Ag + (size_t)n * 8 * Kdim + ko);
      async_ld16(sBw + n * 512, Bg + (size_t)n * 8 * Kdim + ko);
    }
    __syncthreads();   // drains vmcnt, then barrier

    #pragma unroll
    for (int s = 0; s < 2; ++s) {      // two K=32 sub-steps, registers reused
      const int slot = (((s * 4 + quad) ^ (r16 & 7)) * 8);
      bf16x8 af[4], bfr[4];
      #pragma unroll
      for (int mi = 0; mi < 4; ++mi)
        af[mi] = *(const bf16x8*)&sA[(wr + mi * 16 + r16) * 64 + slot];
      #pragma unroll
      for (int ni = 0; ni < 4; ++ni)
        bfr[ni] = *(const bf16x8*)&sB[(wc + ni * 16 + r16) * 64 + slot];

      #pragma unroll
      for (int mi = 0; mi < 4; ++mi)
        #pragma unroll
        for (int ni = 0; ni < 4; ++ni)
          acc[mi][ni] = __builtin_amdgcn_mfma_f32_16x16x32_bf16(af[mi], bfr[ni], acc[mi][ni], 0, 0, 0);
    }

    __syncthreads();   // protect LDS before next stage overwrites
  }

  // C/D layout: col = lane&15, row = (lane>>4)*4 + reg  [measured m89/m91]
  const float scl = (blockIdx.z == 0) ? 0.125f : 1.0f;   // fold 1/sqrt(64) into Q
  const int crow0 = blockIdx.x * 128 + wr + quad * 4;
  const int ccol0 = blockIdx.y * 128 + wc + r16;
  #pragma unroll
  for (int mi = 0; mi < 4; ++mi)
    #pragma unroll
    for (int ni = 0; ni < 4; ++ni)
      #pragma unroll
      for (int r = 0; r < 4; ++r)
        C[(size_t)(crow0 + mi * 16 + r) * DM + (ccol0 + ni * 16)] = (bf16_t)(acc[mi][ni][r] * scl);
}

// ---------- Output projection: 128x64 tile (1024 blocks), BK=64 swizzled, f32 out ----------
__global__ __launch_bounds__(256)
void gemm_out(const bf16_t* __restrict__ A, const bf16_t* __restrict__ B,
              float* __restrict__ C)
{
  constexpr int Kdim = DM;
  __shared__ __attribute__((aligned(16))) bf16_t sA[128 * 64];   // 16 KB
  __shared__ __attribute__((aligned(16))) bf16_t sB[64 * 64];    // 8 KB

  const int tid  = threadIdx.x;
  const int wave = tid >> 6;
  const int lane = tid & 63;
  const int quad = lane >> 4;
  const int r16  = lane & 15;
  const int wr   = (wave >> 1) * 64;   // wave row offset in 128-row tile
  const int wc   = (wave & 1) * 32;    // wave col offset in 64-col tile

  const int gc = (lane & 7) ^ ((lane >> 3) & 7);
  const size_t arow = (size_t)blockIdx.x * 128 + wave * 32 + (lane >> 3);
  const size_t brow = (size_t)blockIdx.y * 64 + wave * 16 + (lane >> 3);
  const bf16_t* Ag = A + arow * Kdim + gc * 8;
  const bf16_t* Bg = B + brow * Kdim + gc * 8;
  bf16_t* sAw = sA + wave * 32 * 64;
  bf16_t* sBw = sB + wave * 16 * 64;

  floatx4 acc[4][2];
  #pragma unroll
  for (int i = 0; i < 4; ++i)
    #pragma unroll
    for (int j = 0; j < 2; ++j)
      acc[i][j] = (floatx4)(0.0f);

  for (int ko = 0; ko < Kdim; ko += 64) {
    #pragma unroll
    for (int n = 0; n < 4; ++n)
      async_ld16(sAw + n * 512, Ag + (size_t)n * 8 * Kdim + ko);
    #pragma unroll
    for (int n = 0; n < 2; ++n)
      async_ld16(sBw + n * 512, Bg + (size_t)n * 8 * Kdim + ko);
    __syncthreads();

    #pragma unroll
    for (int s = 0; s < 2; ++s) {
      const int slot = (((s * 4 + quad) ^ (r16 & 7)) * 8);
      bf16x8 af[4], bfr[2];
      #pragma unroll
      for (int mi = 0; mi < 4; ++mi)
        af[mi] = *(const bf16x8*)&sA[(wr + mi * 16 + r16) * 64 + slot];
      #pragma unroll
      for (int ni = 0; ni < 2; ++ni)
        bfr[ni] = *(const bf16x8*)&sB[(wc + ni * 16 + r16) * 64 + slot];

      #pragma unroll
      for (int mi = 0; mi < 4; ++mi)
        #pragma unroll
        for (int ni = 0; ni < 2; ++ni)
          acc[mi][ni] = __builtin_amdgcn_mfma_f32_16x16x32_bf16(af[mi], bfr[ni], acc[mi][ni], 0, 0, 0);
    }

    __syncthreads();
  }

  const int crow0 = blockIdx.x * 128 + wr + quad * 4;
  const int ccol0 = blockIdx.y * 64 + wc + r16;
  #pragma unroll
  for (int mi = 0; mi < 4; ++mi)
    #pragma unroll
    for (int ni = 0; ni < 2; ++ni)
      #pragma unroll
      for (int r = 0; r < 4; ++r)
        C[(size_t)(crow0 + mi * 16 + r) * DM + (ccol0 + ni * 16)] = acc[mi][ni][r];
}

// ---------- Attention: SPLIT-WAVE (round 10, kept) ----------
// 2 waves per query: wave sub handles positions t = sub, sub+2, ...; partial
// (m, l, acc[16]) states merge through LDS with one exp-rescale.
// Lane L owns dims [16L,16L+16) (head = L>>2); Q arrives pre-scaled.
__global__ __launch_bounds__(256)
void dilated_attn(const bf16_t* __restrict__ Q, const bf16_t* __restrict__ K,
                  const bf16_t* __restrict__ V, bf16_t* O)
{
  __shared__ float sM[2][64];
  __shared__ float sL[2][64];
  __shared__ float sAcc[2][64][17];   // stride 17: gcd(17,32)=1 -> conflict-free

  const int lane = threadIdx.x & 63;
  const int wv   = threadIdx.x >> 6;   // 0..3
  const int ql   = wv >> 1;            // query within block (0,1)
  const int sub  = wv & 1;             // position-parity subset
  const int qb   = (blockIdx.x & 7) * 512 + (blockIdx.x >> 3);  // XCD-affinity swizzle
  const int i    = qb * 2 + ql;
  const size_t base = (size_t)i * DM + lane * 16;

  bf16x8 q0 = *(const bf16x8*)(Q + base);
  bf16x8 q1 = *(const bf16x8*)(Q + base + 8);
  float qf[16];
  #pragma unroll
  for (int j = 0; j < 8; ++j) { qf[j] = (float)q0[j]; qf[j + 8] = (float)q1[j]; }

  // npos = 1 (i==0) else floor(log2 i) + 2   (wave-uniform)
  const int npos = (i == 0) ? 1 : (33 - __builtin_clz((unsigned)i));
  auto pos_addr = [&](int t) -> size_t {
    const int off = (t == 0) ? 0 : (1 << (t - 1));
    return (size_t)(i - off) * DM + lane * 16;
  };

  float m = -INFINITY, l = 0.0f;
  float acc[16];
  #pragma unroll
  for (int j = 0; j < 16; ++j) acc[j] = 0.0f;

  int t = sub;
  if (t < npos) {
    size_t a = pos_addr(t);
    bf16x8 k0 = *(const bf16x8*)(K + a), k1 = *(const bf16x8*)(K + a + 8);
    bf16x8 v0 = *(const bf16x8*)(V + a), v1 = *(const bf16x8*)(V + a + 8);
    while (true) {
      const int tn = t + 2;
      const bool more = (tn < npos);       // wave-uniform
      bf16x8 nk0, nk1, nv0, nv1;
      if (more) {                          // prefetch next position in subset
        const size_t na = pos_addr(tn);
        nk0 = *(const bf16x8*)(K + na); nk1 = *(const bf16x8*)(K + na + 8);
        nv0 = *(const bf16x8*)(V + na); nv1 = *(const bf16x8*)(V + na + 8);
      }

      float sc = 0.0f;
      #pragma unroll
      for (int j = 0; j < 8; ++j) sc += qf[j] * (float)k0[j] + qf[j + 8] * (float)k1[j];
      sc += __shfl_xor(sc, 1, 64);         // sum across the 4 lanes of this head
      sc += __shfl_xor(sc, 2, 64);

      float mn = fmaxf(m, sc);
      float co = __expf(m - mn);
      float w  = __expf(sc - mn);
      l = l * co + w;
      m = mn;
      #pragma unroll
      for (int j = 0; j < 8; ++j) {
        acc[j]     = acc[j]     * co + w * (float)v0[j];
        acc[j + 8] = acc[j + 8] * co + w * (float)v1[j];
      }

      if (!more) break;
      k0 = nk0; k1 = nk1; v0 = nv0; v1 = nv1;
      t = tn;
    }
  }

  // merge the two partial states per query
  if (sub == 1) {
    sM[ql][lane] = m;
    sL[ql][lane] = l;
    #pragma unroll
    for (int j = 0; j < 16; ++j) sAcc[ql][lane][j] = acc[j];
  }
  __syncthreads();
  if (sub == 0) {
    const float mb = sM[ql][lane], lb = sL[ql][lane];
    const float mt = fmaxf(m, mb);           // m finite (t=0 always valid for sub=0)
    const float ca = __expf(m - mt);
    const float cb = __expf(mb - mt);        // mb=-inf (i==0 case) -> cb=0, exact no-op
    const float inv = 1.0f / (l * ca + lb * cb);
    bf16x8 o0, o1;
    #pragma unroll
    for (int j = 0; j < 8; ++j) {
      o0[j] = (bf16_t)((acc[j]     * ca + sAcc[ql][lane][j]     * cb) * inv);
      o1[j] = (bf16_t)((acc[j + 8] * ca + sAcc[ql][lane][j + 8] * cb) * inv);
    }
    *(bf16x8*)(O + base)     = o0;
    *(bf16x8*)(O + base + 8) = o1;
  }
}

extern "C" void kernel_launch(void* const* d_in, const int* in_sizes, int n_in,
                              void* d_out, int out_size, void* d_ws, size_t ws_size,
                              hipStream_t stream) {
  (void)in_sizes; (void)n_in; (void)out_size; (void)ws_size;
  const float* x  = (const float*)d_in[0];
  const float* qw = (const float*)d_in[1];
  const float* kw = (const float*)d_in[2];
  const float* vw = (const float*)d_in[3];
  const float* ow = (const float*)d_in[4];
  // d_in[5] (positions) and d_in[6] (attend_mask) recomputed analytically in-kernel
  float* out = (float*)d_out;

  bf16_t* Xb  = (bf16_t*)d_ws;                       // 8192x1024
  bf16_t* Qb  = Xb  + (size_t)SEQ * DM;
  bf16_t* Kb  = Qb  + (size_t)SEQ * DM;
  bf16_t* Vb  = Kb  + (size_t)SEQ * DM;
  bf16_t* QWb = Vb  + (size_t)SEQ * DM;              // 1024x1024 x4
  bf16_t* KWb = QWb + (size_t)DM * DM;
  bf16_t* VWb = KWb + (size_t)DM * DM;
  bf16_t* OWb = VWb + (size_t)DM * DM;
  bf16_t* AO  = Qb;  // alias Q: each attn block reads its own q rows before writing them

  cvt_all<<<dim3(8192 + 4096), dim3(256), 0, stream>>>(x, qw, kw, vw, ow,
                                                       Xb, QWb, KWb, VWb, OWb);

  dim3 block(256);
  gemm_qkv<<<dim3(SEQ / 128, DM / 128, 3), block, 0, stream>>>(Xb, QWb, KWb, VWb, Qb, Kb, Vb);
  dilated_attn<<<dim3(SEQ / 2), block, 0, stream>>>(Qb, Kb, Vb, AO);
  gemm_out<<<dim3(SEQ / 128, DM / 64), block, 0, stream>>>(AO, OWb, out);
}

// Round 13
// 217.618 us; speedup vs baseline: 1.0192x; 1.0192x over previous
//
#include <hip/hip_runtime.h>
#include <hip/hip_bf16.h>

typedef __bf16 bf16_t;
typedef __bf16 bf16x4 __attribute__((ext_vector_type(4)));
typedef __bf16 bf16x8 __attribute__((ext_vector_type(8)));
typedef float floatx16 __attribute__((ext_vector_type(16)));

#define SEQ    8192
#define DM     1024
#define NHEADS 16
#define HDIM   64

// async global->LDS, 16B per lane; LDS dest is wave-uniform base + lane*16
__device__ __forceinline__ void async_ld16(bf16_t* lds, const bf16_t* g) {
  __builtin_amdgcn_global_load_lds(
      (__attribute__((address_space(1))) void*)g,
      (__attribute__((address_space(3))) void*)lds, 16, 0, 0);
}

// one launch converts x (8192 blocks) + 4 weight matrices (1024 blocks each)
__global__ __launch_bounds__(256)
void cvt_all(const float* __restrict__ x,  const float* __restrict__ qw,
             const float* __restrict__ kw, const float* __restrict__ vw,
             const float* __restrict__ ow,
             bf16_t* __restrict__ Xb,  bf16_t* __restrict__ QWb,
             bf16_t* __restrict__ KWb, bf16_t* __restrict__ VWb,
             bf16_t* __restrict__ OWb) {
  const int b = blockIdx.x;
  const float* in; bf16_t* out; int g;
  if (b < 8192) { in = x; out = Xb; g = b; }
  else {
    const int w  = (b - 8192) >> 10;
    const int wb = (b - 8192) & 1023;
    switch (w) {
      case 0:  in = qw; out = QWb; break;
      case 1:  in = kw; out = KWb; break;
      case 2:  in = vw; out = VWb; break;
      default: in = ow; out = OWb; break;
    }
    g = wb;
  }
  const int idx = (g * 256 + threadIdx.x) * 4;
  float4 v = *(const float4*)(in + idx);
  bf16x4 o = { (bf16_t)v.x, (bf16_t)v.y, (bf16_t)v.z, (bf16_t)v.w };
  *(bf16x4*)(out + idx) = o;
}

// ---------- QKV projection: 128x128 tile, BK=64, 32x32x16 MFMA ----------
// MFMA shape switch: v_mfma_f32_32x32x16_bf16 runs 2382-2495 TF vs 2075-2176 for
// 16x16x32 (m06/m119) and halves MFMA instruction count. Wave tile 64x64 = 2x2
// tiles of 32x32; per K=64 step: 4 sub-steps x (4 ds_read_b128 + 4 MFMA).
// A/B frag: m=lane&31, k=(lane>>5)*8+j. C/D: col=lane&31,
// row=(reg&3)+8*(reg>>2)+4*(lane>>5) [measured m74/m101].
// LDS: BK=64 XOR-8 swizzle (round 12, conflicts=0): slot c of row r holds
// global chunk c^(r&7); 32-row x 2-half read = 8 lanes/bank-group (perfect).
__global__ __launch_bounds__(256)
void gemm_qkv(const bf16_t* __restrict__ A,
              const bf16_t* __restrict__ Bq, const bf16_t* __restrict__ Bk,
              const bf16_t* __restrict__ Bv,
              bf16_t* __restrict__ Cq, bf16_t* __restrict__ Ck, bf16_t* __restrict__ Cv)
{
  const bf16_t* B = (blockIdx.z == 0) ? Bq : (blockIdx.z == 1) ? Bk : Bv;
  bf16_t*       C = (blockIdx.z == 0) ? Cq : (blockIdx.z == 1) ? Ck : Cv;
  constexpr int Kdim = DM;
  __shared__ __attribute__((aligned(16))) bf16_t sA[128 * 64];   // 16 KB
  __shared__ __attribute__((aligned(16))) bf16_t sB[128 * 64];   // 16 KB

  const int tid  = threadIdx.x;
  const int wave = tid >> 6;
  const int lane = tid & 63;
  const int l31  = lane & 31;
  const int half = lane >> 5;
  const int wr   = (wave >> 1) * 64;
  const int wc   = (wave & 1) * 64;

  const int gc = (lane & 7) ^ ((lane >> 3) & 7);   // swizzled fetch chunk
  const size_t arow0 = (size_t)blockIdx.x * 128 + wave * 32 + (lane >> 3);
  const size_t brow0 = (size_t)blockIdx.y * 128 + wave * 32 + (lane >> 3);
  const bf16_t* Ag = A + arow0 * Kdim + gc * 8;
  const bf16_t* Bg = B + brow0 * Kdim + gc * 8;
  bf16_t* sAw = sA + wave * 32 * 64;
  bf16_t* sBw = sB + wave * 32 * 64;

  floatx16 acc[2][2];
  #pragma unroll
  for (int i = 0; i < 2; ++i)
    #pragma unroll
    for (int j = 0; j < 2; ++j)
      acc[i][j] = (floatx16)(0.0f);

  const int sw = l31 & 7;                 // read-side swizzle key (rows = l31 mod 8)

  for (int ko = 0; ko < Kdim; ko += 64) {
    #pragma unroll
    for (int n = 0; n < 4; ++n) {
      async_ld16(sAw + n * 512, Ag + (size_t)n * 8 * Kdim + ko);
      async_ld16(sBw + n * 512, Bg + (size_t)n * 8 * Kdim + ko);
    }
    __syncthreads();   // drains vmcnt, then barrier

    #pragma unroll
    for (int s = 0; s < 4; ++s) {         // four K=16 sub-steps
      const int ck   = s * 2 + half;      // 16B chunk within 128B row
      const int slot = (ck ^ sw) * 8;     // swizzled slot (elements)
      bf16x8 af[2], bfr[2];
      #pragma unroll
      for (int mi = 0; mi < 2; ++mi)
        af[mi] = *(const bf16x8*)&sA[(wr + mi * 32 + l31) * 64 + slot];
      #pragma unroll
      for (int ni = 0; ni < 2; ++ni)
        bfr[ni] = *(const bf16x8*)&sB[(wc + ni * 32 + l31) * 64 + slot];

      #pragma unroll
      for (int mi = 0; mi < 2; ++mi)
        #pragma unroll
        for (int ni = 0; ni < 2; ++ni)
          acc[mi][ni] = __builtin_amdgcn_mfma_f32_32x32x16_bf16(af[mi], bfr[ni], acc[mi][ni], 0, 0, 0);
    }

    __syncthreads();   // protect LDS before next stage overwrites
  }

  // C/D: col = lane&31, row = (reg&3) + 8*(reg>>2) + 4*(lane>>5)  [m74/m101]
  const float scl = (blockIdx.z == 0) ? 0.125f : 1.0f;   // fold 1/sqrt(64) into Q
  const int crow0 = blockIdx.x * 128 + wr + 4 * half;
  const int ccol0 = blockIdx.y * 128 + wc + l31;
  #pragma unroll
  for (int mi = 0; mi < 2; ++mi)
    #pragma unroll
    for (int ni = 0; ni < 2; ++ni)
      #pragma unroll
      for (int r = 0; r < 16; ++r) {
        const int row = crow0 + mi * 32 + (r & 3) + 8 * (r >> 2);
        C[(size_t)row * DM + (ccol0 + ni * 32)] = (bf16_t)(acc[mi][ni][r] * scl);
      }
}

// ---------- Output projection: 128x64 tile (1024 blocks), BK=32, 32x32x16 MFMA ----------
// Wave tile 64x32 = 2x1 tiles of 32x32. BK=32 XOR-4 swizzle (round 8):
// slot c of row r holds global chunk c^((r>>1)&3).
__global__ __launch_bounds__(256)
void gemm_out(const bf16_t* __restrict__ A, const bf16_t* __restrict__ B,
              float* __restrict__ C)
{
  constexpr int Kdim = DM;
  __shared__ __attribute__((aligned(16))) bf16_t sA[128 * 32];
  __shared__ __attribute__((aligned(16))) bf16_t sB[64 * 32];

  const int tid  = threadIdx.x;
  const int wave = tid >> 6;
  const int lane = tid & 63;
  const int l31  = lane & 31;
  const int half = lane >> 5;
  const int wr   = (wave >> 1) * 64;   // wave row offset in 128-row tile
  const int wc   = (wave & 1) * 32;    // wave col offset in 64-col tile

  const int gc = (lane & 3) ^ ((lane >> 3) & 3);
  const size_t arow = (size_t)blockIdx.x * 128 + wave * 32 + (lane >> 2);
  const size_t brow = (size_t)blockIdx.y * 64 + wave * 16 + (lane >> 2);
  const bf16_t* Ag = A + arow * Kdim + gc * 8;
  const bf16_t* Bg = B + brow * Kdim + gc * 8;
  bf16_t* sAw = sA + wave * 32 * 32;
  bf16_t* sBw = sB + wave * 16 * 32;

  floatx16 acc[2];
  acc[0] = (floatx16)(0.0f);
  acc[1] = (floatx16)(0.0f);

  const int sw = (l31 >> 1) & 3;          // read-side swizzle key

  for (int ko = 0; ko < Kdim; ko += 32) {
    async_ld16(sAw,           Ag + ko);
    async_ld16(sAw + 16 * 32, Ag + 16 * Kdim + ko);
    async_ld16(sBw,           Bg + ko);
    __syncthreads();

    #pragma unroll
    for (int s = 0; s < 2; ++s) {         // two K=16 sub-steps
      const int ck   = s * 2 + half;      // 16B chunk within 64B row
      const int slot = (ck ^ sw) * 8;
      bf16x8 af[2], bfr;
      #pragma unroll
      for (int mi = 0; mi < 2; ++mi)
        af[mi] = *(const bf16x8*)&sA[(wr + mi * 32 + l31) * 32 + slot];
      bfr = *(const bf16x8*)&sB[(wc + l31) * 32 + slot];

      #pragma unroll
      for (int mi = 0; mi < 2; ++mi)
        acc[mi] = __builtin_amdgcn_mfma_f32_32x32x16_bf16(af[mi], bfr, acc[mi], 0, 0, 0);
    }

    __syncthreads();
  }

  const int crow0 = blockIdx.x * 128 + wr + 4 * half;
  const int ccol  = blockIdx.y * 64 + wc + l31;
  #pragma unroll
  for (int mi = 0; mi < 2; ++mi)
    #pragma unroll
    for (int r = 0; r < 16; ++r) {
      const int row = crow0 + mi * 32 + (r & 3) + 8 * (r >> 2);
      C[(size_t)row * DM + ccol] = acc[mi][r];
    }
}

// ---------- Attention: SPLIT-WAVE (round 10, kept) ----------
// 2 waves per query: wave sub handles positions t = sub, sub+2, ...; partial
// (m, l, acc[16]) states merge through LDS with one exp-rescale.
// Lane L owns dims [16L,16L+16) (head = L>>2); Q arrives pre-scaled.
__global__ __launch_bounds__(256)
void dilated_attn(const bf16_t* __restrict__ Q, const bf16_t* __restrict__ K,
                  const bf16_t* __restrict__ V, bf16_t* O)
{
  __shared__ float sM[2][64];
  __shared__ float sL[2][64];
  __shared__ float sAcc[2][64][17];   // stride 17: gcd(17,32)=1 -> conflict-free

  const int lane = threadIdx.x & 63;
  const int wv   = threadIdx.x >> 6;   // 0..3
  const int ql   = wv >> 1;            // query within block (0,1)
  const int sub  = wv & 1;             // position-parity subset
  const int qb   = (blockIdx.x & 7) * 512 + (blockIdx.x >> 3);  // XCD-affinity swizzle
  const int i    = qb * 2 + ql;
  const size_t base = (size_t)i * DM + lane * 16;

  bf16x8 q0 = *(const bf16x8*)(Q + base);
  bf16x8 q1 = *(const bf16x8*)(Q + base + 8);
  float qf[16];
  #pragma unroll
  for (int j = 0; j < 8; ++j) { qf[j] = (float)q0[j]; qf[j + 8] = (float)q1[j]; }

  // npos = 1 (i==0) else floor(log2 i) + 2   (wave-uniform)
  const int npos = (i == 0) ? 1 : (33 - __builtin_clz((unsigned)i));
  auto pos_addr = [&](int t) -> size_t {
    const int off = (t == 0) ? 0 : (1 << (t - 1));
    return (size_t)(i - off) * DM + lane * 16;
  };

  float m = -INFINITY, l = 0.0f;
  float acc[16];
  #pragma unroll
  for (int j = 0; j < 16; ++j) acc[j] = 0.0f;

  int t = sub;
  if (t < npos) {
    size_t a = pos_addr(t);
    bf16x8 k0 = *(const bf16x8*)(K + a), k1 = *(const bf16x8*)(K + a + 8);
    bf16x8 v0 = *(const bf16x8*)(V + a), v1 = *(const bf16x8*)(V + a + 8);
    while (true) {
      const int tn = t + 2;
      const bool more = (tn < npos);       // wave-uniform
      bf16x8 nk0, nk1, nv0, nv1;
      if (more) {                          // prefetch next position in subset
        const size_t na = pos_addr(tn);
        nk0 = *(const bf16x8*)(K + na); nk1 = *(const bf16x8*)(K + na + 8);
        nv0 = *(const bf16x8*)(V + na); nv1 = *(const bf16x8*)(V + na + 8);
      }

      float sc = 0.0f;
      #pragma unroll
      for (int j = 0; j < 8; ++j) sc += qf[j] * (float)k0[j] + qf[j + 8] * (float)k1[j];
      sc += __shfl_xor(sc, 1, 64);         // sum across the 4 lanes of this head
      sc += __shfl_xor(sc, 2, 64);

      float mn = fmaxf(m, sc);
      float co = __expf(m - mn);
      float w  = __expf(sc - mn);
      l = l * co + w;
      m = mn;
      #pragma unroll
      for (int j = 0; j < 8; ++j) {
        acc[j]     = acc[j]     * co + w * (float)v0[j];
        acc[j + 8] = acc[j + 8] * co + w * (float)v1[j];
      }

      if (!more) break;
      k0 = nk0; k1 = nk1; v0 = nv0; v1 = nv1;
      t = tn;
    }
  }

  // merge the two partial states per query
  if (sub == 1) {
    sM[ql][lane] = m;
    sL[ql][lane] = l;
    #pragma unroll
    for (int j = 0; j < 16; ++j) sAcc[ql][lane][j] = acc[j];
  }
  __syncthreads();
  if (sub == 0) {
    const float mb = sM[ql][lane], lb = sL[ql][lane];
    const float mt = fmaxf(m, mb);           // m finite (t=0 always valid for sub=0)
    const float ca = __expf(m - mt);
    const float cb = __expf(mb - mt);        // mb=-inf (i==0 case) -> cb=0, exact no-op
    const float inv = 1.0f / (l * ca + lb * cb);
    bf16x8 o0, o1;
    #pragma unroll
    for (int j = 0; j < 8; ++j) {
      o0[j] = (bf16_t)((acc[j]     * ca + sAcc[ql][lane][j]     * cb) * inv);
      o1[j] = (bf16_t)((acc[j + 8] * ca + sAcc[ql][lane][j + 8] * cb) * inv);
    }
    *(bf16x8*)(O + base)     = o0;
    *(bf16x8*)(O + base + 8) = o1;
  }
}

extern "C" void kernel_launch(void* const* d_in, const int* in_sizes, int n_in,
                              void* d_out, int out_size, void* d_ws, size_t ws_size,
                              hipStream_t stream) {
  (void)in_sizes; (void)n_in; (void)out_size; (void)ws_size;
  const float* x  = (const float*)d_in[0];
  const float* qw = (const float*)d_in[1];
  const float* kw = (const float*)d_in[2];
  const float* vw = (const float*)d_in[3];
  const float* ow = (const float*)d_in[4];
  // d_in[5] (positions) and d_in[6] (attend_mask) recomputed analytically in-kernel
  float* out = (float*)d_out;

  bf16_t* Xb  = (bf16_t*)d_ws;                       // 8192x1024
  bf16_t* Qb  = Xb  + (size_t)SEQ * DM;
  bf16_t* Kb  = Qb  + (size_t)SEQ * DM;
  bf16_t* Vb  = Kb  + (size_t)SEQ * DM;
  bf16_t* QWb = Vb  + (size_t)SEQ * DM;              // 1024x1024 x4
  bf16_t* KWb = QWb + (size_t)DM * DM;
  bf16_t* VWb = KWb + (size_t)DM * DM;
  bf16_t* OWb = VWb + (size_t)DM * DM;
  bf16_t* AO  = Qb;  // alias Q: each attn block reads its own q rows before writing them

  cvt_all<<<dim3(8192 + 4096), dim3(256), 0, stream>>>(x, qw, kw, vw, ow,
                                                       Xb, QWb, KWb, VWb, OWb);

  dim3 block(256);
  gemm_qkv<<<dim3(SEQ / 128, DM / 128, 3), block, 0, stream>>>(Xb, QWb, KWb, VWb, Qb, Kb, Vb);
  dilated_attn<<<dim3(SEQ / 2), block, 0, stream>>>(Qb, Kb, Vb, AO);
  gemm_out<<<dim3(SEQ / 128, DM / 64), block, 0, stream>>>(AO, OWb, out);
}